// Round 1
// baseline (6422.144 us; speedup 1.0000x reference)
//
#include <hip/hip_runtime.h>
#include <math.h>

// Problem constants
#define BB 8
#define LL 4096
#define DD 512
#define PTOT (BB*LL)      // 32768 positions
#define HID  2048         // 4*D

// ---------------------------------------------------------------------------
// Weight transpose: W (o, c, k) -> Wt[(k*512 + c)*512 + o]
__global__ __launch_bounds__(256) void transpose_w(const float* __restrict__ W,
                                                   float* __restrict__ Wt, int K) {
    int tid = blockIdx.x * 256 + threadIdx.x;
    if (tid >= DD * DD * K) return;
    int o  = tid & (DD - 1);
    int ck = tid >> 9;           // c + 512*k
    int c  = ck & (DD - 1);
    int k  = ck >> 9;
    Wt[tid] = W[(o * DD + c) * K + k];
}

// ---------------------------------------------------------------------------
// srcp[p*K + k] = source row (p + k - pad) if in-bounds and chain matches, else -1
__global__ __launch_bounds__(256) void make_srcp(const int* __restrict__ chain,
                                                 int* __restrict__ srcp, int K) {
    int tid = blockIdx.x * 256 + threadIdx.x;
    if (tid >= PTOT * K) return;
    int p = tid / K;
    int k = tid - p * K;
    int b = p >> 12;             // /4096
    int l = p & (LL - 1);
    int pad = (K - 1) >> 1;
    int l2 = l + k - pad;
    bool ok = (l2 >= 0) && (l2 < LL) && (chain[b * LL + l2] == chain[b * LL + l]);
    srcp[tid] = ok ? (p + k - pad) : -1;
}

// ---------------------------------------------------------------------------
// Masked conv as GEMM: Y[p,o] = bias[o] + sum_{k,c} A_k[p,c] * Wt[(k*512+c), o]
// Tile: BM=64 x BN=64 x BK=16, 256 threads, 4x4 microtile.
template <int K>
__global__ __launch_bounds__(256) void conv_gemm(const float* __restrict__ X,
                                                 const int* __restrict__ srcp,
                                                 const float* __restrict__ Wt,
                                                 const float* __restrict__ bias,
                                                 float* __restrict__ Y) {
    const int BM = 64, BN = 64, BK = 16;
    __shared__ float As[BK][BM + 4];   // +4 pad: keeps 16B align, kills 16-way store conflict
    __shared__ float Bs[BK][BN];
    int t = threadIdx.x;
    int trow = t >> 4;                 // 0..15
    int tcol = t & 15;                 // 0..15
    int p0 = blockIdx.x * BM;
    int o0 = blockIdx.y * BN;
    float acc[4][4] = {};

    for (int kt = 0; kt < K * DD; kt += BK) {
        int ktap  = kt >> 9;           // constant within tile (512 % 16 == 0)
        int cbase = kt & (DD - 1);
#pragma unroll
        for (int i = 0; i < 4; i++) {  // A tile: 1024 elems
            int e  = i * 256 + t;
            int r  = e >> 4;           // row within tile
            int kk = e & 15;
            int sp = srcp[(p0 + r) * K + ktap];
            float v = 0.f;
            if (sp >= 0) v = X[(size_t)sp * DD + cbase + kk];
            As[kk][r] = v;
        }
#pragma unroll
        for (int i = 0; i < 4; i++) {  // B tile: 1024 elems
            int e   = i * 256 + t;
            int kk  = e >> 6;
            int col = e & 63;
            Bs[kk][col] = Wt[(size_t)(kt + kk) * DD + o0 + col];
        }
        __syncthreads();
#pragma unroll
        for (int kk = 0; kk < BK; kk++) {
            float a[4], b[4];
#pragma unroll
            for (int i = 0; i < 4; i++) a[i] = As[kk][trow * 4 + i];
#pragma unroll
            for (int j = 0; j < 4; j++) b[j] = Bs[kk][tcol * 4 + j];
#pragma unroll
            for (int i = 0; i < 4; i++)
#pragma unroll
                for (int j = 0; j < 4; j++) acc[i][j] += a[i] * b[j];
        }
        __syncthreads();
    }
#pragma unroll
    for (int i = 0; i < 4; i++) {
        int p = p0 + trow * 4 + i;
#pragma unroll
        for (int j = 0; j < 4; j++) {
            int o = o0 + tcol * 4 + j;
            Y[(size_t)p * DD + o] = acc[i][j] + bias[o];
        }
    }
}

// ---------------------------------------------------------------------------
__device__ __forceinline__ float gelu_tanh(float x) {
    // JAX default: approximate=True (tanh form)
    float x3 = x * x * x;
    return 0.5f * x * (1.f + tanhf(0.7978845608028654f * (x + 0.044715f * x3)));
}

// Plain GEMM, 64x64x16 tile. EPI=0: C = gelu(acc + bias); EPI=1: C += acc
template <int EPI>
__global__ __launch_bounds__(256) void gemm_k(const float* __restrict__ A, int lda,
                                              const float* __restrict__ Bm, int ldb,
                                              const float* __restrict__ bias,
                                              float* __restrict__ C, int ldc,
                                              int Kdim) {
    const int BM = 64, BN = 64, BK = 16;
    __shared__ float As[BK][BM + 4];
    __shared__ float Bs[BK][BN];
    int t = threadIdx.x;
    int trow = t >> 4;
    int tcol = t & 15;
    int p0 = blockIdx.x * BM;
    int o0 = blockIdx.y * BN;
    float acc[4][4] = {};

    for (int kt = 0; kt < Kdim; kt += BK) {
#pragma unroll
        for (int i = 0; i < 4; i++) {
            int e  = i * 256 + t;
            int r  = e >> 4;
            int kk = e & 15;
            As[kk][r] = A[(size_t)(p0 + r) * lda + kt + kk];
        }
#pragma unroll
        for (int i = 0; i < 4; i++) {
            int e   = i * 256 + t;
            int kk  = e >> 6;
            int col = e & 63;
            Bs[kk][col] = Bm[(size_t)(kt + kk) * ldb + o0 + col];
        }
        __syncthreads();
#pragma unroll
        for (int kk = 0; kk < BK; kk++) {
            float a[4], b[4];
#pragma unroll
            for (int i = 0; i < 4; i++) a[i] = As[kk][trow * 4 + i];
#pragma unroll
            for (int j = 0; j < 4; j++) b[j] = Bs[kk][tcol * 4 + j];
#pragma unroll
            for (int i = 0; i < 4; i++)
#pragma unroll
                for (int j = 0; j < 4; j++) acc[i][j] += a[i] * b[j];
        }
        __syncthreads();
    }
#pragma unroll
    for (int i = 0; i < 4; i++) {
        int p = p0 + trow * 4 + i;
#pragma unroll
        for (int j = 0; j < 4; j++) {
            int o = o0 + tcol * 4 + j;
            if (EPI == 0) {
                C[(size_t)p * ldc + o] = gelu_tanh(acc[i][j] + bias[o]);
            } else {
                C[(size_t)p * ldc + o] += acc[i][j];
            }
        }
    }
}

// ---------------------------------------------------------------------------
// LayerNorm over D of (A + Bsrc), one block per position, 256 threads x 2 elems
__global__ __launch_bounds__(256) void ln_kernel(const float* __restrict__ A,
                                                 const float* __restrict__ Bsrc,
                                                 const float* __restrict__ g,
                                                 const float* __restrict__ beta,
                                                 float* __restrict__ Out) {
    int p = blockIdx.x;
    int t = threadIdx.x;
    size_t base = (size_t)p * DD;
    float v0 = A[base + t] + Bsrc[base + t];
    float v1 = A[base + 256 + t] + Bsrc[base + 256 + t];
    float s  = v0 + v1;
    float sq = v0 * v0 + v1 * v1;
#pragma unroll
    for (int off = 32; off > 0; off >>= 1) {
        s  += __shfl_xor(s, off);
        sq += __shfl_xor(sq, off);
    }
    __shared__ float red[2][4];
    int wid = t >> 6, lane = t & 63;
    if (lane == 0) { red[0][wid] = s; red[1][wid] = sq; }
    __syncthreads();
    float S  = red[0][0] + red[0][1] + red[0][2] + red[0][3];
    float SQ = red[1][0] + red[1][1] + red[1][2] + red[1][3];
    float mu  = S * (1.f / DD);
    float var = SQ * (1.f / DD) - mu * mu;
    float rs  = rsqrtf(var + 1e-5f);
    Out[base + t]       = (v0 - mu) * rs * g[t] + beta[t];
    Out[base + 256 + t] = (v1 - mu) * rs * g[256 + t] + beta[256 + t];
}

// ---------------------------------------------------------------------------
__global__ __launch_bounds__(256) void init_out(const float* __restrict__ b2,
                                                float* __restrict__ C) {
    int idx = blockIdx.x * 256 + threadIdx.x;
    C[idx] = b2[idx & (DD - 1)];
}

// ---------------------------------------------------------------------------
extern "C" void kernel_launch(void* const* d_in, const int* in_sizes, int n_in,
                              void* d_out, int out_size, void* d_ws, size_t ws_size,
                              hipStream_t stream) {
    const float* x     = (const float*)d_in[0];
    const int*   chain = (const int*)d_in[1];
    const float* W3    = (const float*)d_in[2];
    const float* b3    = (const float*)d_in[3];
    const float* W5    = (const float*)d_in[4];
    const float* b5    = (const float*)d_in[5];
    const float* W7    = (const float*)d_in[6];
    const float* b7    = (const float*)d_in[7];
    const float* w1    = (const float*)d_in[8];
    const float* bm1   = (const float*)d_in[9];
    const float* w2    = (const float*)d_in[10];
    const float* bm2   = (const float*)d_in[11];
    const float* g1    = (const float*)d_in[12];
    const float* be1   = (const float*)d_in[13];
    const float* g2    = (const float*)d_in[14];
    const float* be2   = (const float*)d_in[15];
    float* out = (float*)d_out;

    // Workspace layout (needs ~146 MB)
    char* ws = (char*)d_ws;
    const size_t BUF = (size_t)PTOT * DD * 4;   // 64 MB
    float* buf1 = (float*)ws;
    float* buf2 = (float*)(ws + BUF);
    float* wt3  = (float*)(ws + 2 * BUF);
    float* wt5  = wt3 + DD * DD * 3;
    float* wt7  = wt5 + DD * DD * 5;
    int*   srcp = (int*)(wt7 + DD * DD * 7);    // PTOT*7 ints, reused per conv

    transpose_w<<<(DD * DD * 3 + 255) / 256, 256, 0, stream>>>(W3, wt3, 3);
    transpose_w<<<(DD * DD * 5 + 255) / 256, 256, 0, stream>>>(W5, wt5, 5);
    transpose_w<<<(DD * DD * 7 + 255) / 256, 256, 0, stream>>>(W7, wt7, 7);

    dim3 grd(PTOT / 64, DD / 64);   // 512 x 8

    make_srcp<<<(PTOT * 3 + 255) / 256, 256, 0, stream>>>(chain, srcp, 3);
    conv_gemm<3><<<grd, 256, 0, stream>>>(x, srcp, wt3, b3, buf1);
    make_srcp<<<(PTOT * 5 + 255) / 256, 256, 0, stream>>>(chain, srcp, 5);
    conv_gemm<5><<<grd, 256, 0, stream>>>(buf1, srcp, wt5, b5, buf2);
    make_srcp<<<(PTOT * 7 + 255) / 256, 256, 0, stream>>>(chain, srcp, 7);
    conv_gemm<7><<<grd, 256, 0, stream>>>(buf2, srcp, wt7, b7, buf1);

    // h = LN1(x + conv_out) -> buf2
    ln_kernel<<<PTOT, 256, 0, stream>>>(x, buf1, g1, be1, buf2);

    // out = b2 (accumulator init)
    init_out<<<PTOT * DD / 256, 256, 0, stream>>>(bm2, out);

    // MLP in 4 chunks of 512 hidden columns: buf1 = gelu(h@w1_chunk + b1); out += buf1@w2_chunk
    for (int jc = 0; jc < 4; jc++) {
        gemm_k<0><<<grd, 256, 0, stream>>>(buf2, DD, w1 + jc * 512, HID,
                                           bm1 + jc * 512, buf1, DD, DD);
        gemm_k<1><<<grd, 256, 0, stream>>>(buf1, DD, w2 + (size_t)(jc * 512) * DD, DD,
                                           nullptr, out, DD, DD);
    }

    // out = LN2(h + out) in place
    ln_kernel<<<PTOT, 256, 0, stream>>>(buf2, out, g2, be2, out);
}

// Round 2
// 935.444 us; speedup vs baseline: 6.8653x; 6.8653x over previous
//
#include <hip/hip_runtime.h>
#include <math.h>

#define BB 8
#define LL 4096
#define DD 512
#define PTOT (BB*LL)      // 32768 positions
#define HID  2048

typedef __attribute__((ext_vector_type(8))) short short8;   // 8 bf16 (4 VGPRs)
typedef __attribute__((ext_vector_type(4))) float f32x4;

__device__ __forceinline__ unsigned short f2bf(float f) {
    union { float f; unsigned int u; } v; v.f = f;
    unsigned int r = v.u + 0x7fffu + ((v.u >> 16) & 1u);
    return (unsigned short)(r >> 16);
}
__device__ __forceinline__ float bf2f(unsigned short h) {
    union { unsigned int u; float f; } v; v.u = ((unsigned int)h) << 16;
    return v.f;
}
__device__ __forceinline__ float gelu_tanh(float x) {
    float x3 = x * x * x;
    return 0.5f * x * (1.f + tanhf(0.7978845608028654f * (x + 0.044715f * x3)));
}

// ---------------------------------------------------------------------------
// x fp32 -> bf16, 4 elems/thread
__global__ __launch_bounds__(256) void convert_x(const float* __restrict__ x,
                                                 unsigned short* __restrict__ xb) {
    int tid = blockIdx.x * 256 + threadIdx.x;
    float4 v = ((const float4*)x)[tid];
    uint2 o;
    o.x = (unsigned int)f2bf(v.x) | ((unsigned int)f2bf(v.y) << 16);
    o.y = (unsigned int)f2bf(v.z) | ((unsigned int)f2bf(v.w) << 16);
    ((uint2*)xb)[tid] = o;
}

// conv W (o,c,k) -> Wt[o][k*512+c] bf16
__global__ __launch_bounds__(256) void trans_wconv(const float* __restrict__ W,
                                                   unsigned short* __restrict__ Wt, int K) {
    int tid = blockIdx.x * 256 + threadIdx.x;
    if (tid >= DD * DD * K) return;
    int o  = tid / (K * DD);
    int kc = tid - o * K * DD;
    int k  = kc >> 9;
    int c  = kc & (DD - 1);
    Wt[tid] = f2bf(W[(o * DD + c) * K + k]);
}

// mlp_w1 (c, n) -> W1t[n][c]
__global__ __launch_bounds__(256) void trans_w1(const float* __restrict__ W,
                                                unsigned short* __restrict__ Wt) {
    int tid = blockIdx.x * 256 + threadIdx.x;   // n*512 + c
    int n = tid >> 9;
    int c = tid & (DD - 1);
    Wt[tid] = f2bf(W[c * HID + n]);
}

// mlp_w2 (h, n) -> W2t[n][h]
__global__ __launch_bounds__(256) void trans_w2(const float* __restrict__ W,
                                                unsigned short* __restrict__ Wt) {
    int tid = blockIdx.x * 256 + threadIdx.x;   // n*2048 + h
    int n = tid >> 11;
    int h = tid & (HID - 1);
    Wt[tid] = f2bf(W[h * DD + n]);
}

// srcp[p*K + k] = p + k - pad if in-range and chain matches, else -1
__global__ __launch_bounds__(256) void make_srcp(const int* __restrict__ chain,
                                                 int* __restrict__ srcp, int K) {
    int tid = blockIdx.x * 256 + threadIdx.x;
    if (tid >= PTOT * K) return;
    int p = tid / K;
    int k = tid - p * K;
    int b = p >> 12;
    int l = p & (LL - 1);
    int pad = (K - 1) >> 1;
    int l2 = l + k - pad;
    bool ok = (l2 >= 0) && (l2 < LL) && (chain[b * LL + l2] == chain[b * LL + l]);
    srcp[tid] = ok ? (p + k - pad) : -1;
}

// ---------------------------------------------------------------------------
// MFMA GEMM: block tile 256x128, 4 waves (2x2), wave tile 128x64 (8x4 frags).
// A: bf16 [M][lda] rows (gathered through srcp when TAPS>0, col range 512/tap).
// Bt: bf16 B^T rows [n][ldb] (contiguous in k).
// EPI: 0 = bf16 out = acc+bias; 1 = bf16 out = gelu(acc+bias);
//      2 = f32 out = acc+bias;  3 = f32 out += acc.
template <int TAPS, int EPI>
__global__ __launch_bounds__(256, 2) void mfma_gemm(
        const unsigned short* __restrict__ A, int lda,
        const int* __restrict__ srcp,
        const unsigned short* __restrict__ Bt, int ldb,
        const float* __restrict__ bias,
        void* __restrict__ Yv, int ldc, int Kspan) {
    const int PITCH = 40;                       // bf16 elems per LDS row (pad 32->40)
    __shared__ alignas(16) unsigned short lds[256 * PITCH + 128 * PITCH];
    unsigned short* As = lds;                   // 256 rows x PITCH
    unsigned short* Bs = lds + 256 * PITCH;     // 128 rows x PITCH

    int t = threadIdx.x;
    int p0 = blockIdx.x * 256;
    int o0 = blockIdx.y * 128;

    int wave = t >> 6, lane = t & 63;
    int wr = wave & 1, wc = wave >> 1;
    int lm = lane & 15, q = lane >> 4;

    int srow = t >> 2;            // 0..63 staging row-within-pass
    int col8 = (t & 3) * 8;       // 0,8,16,24

    f32x4 acc[8][4];
#pragma unroll
    for (int mi = 0; mi < 8; mi++)
#pragma unroll
        for (int nj = 0; nj < 4; nj++) acc[mi][nj] = (f32x4){0.f, 0.f, 0.f, 0.f};

    const int NT = TAPS ? TAPS : 1;
    for (int tap = 0; tap < NT; ++tap) {
        int sp[4];
#pragma unroll
        for (int i = 0; i < 4; i++) {
            int r = i * 64 + srow;
            sp[i] = TAPS ? srcp[(p0 + r) * TAPS + tap] : (p0 + r);
        }
        const int span = TAPS ? DD : Kspan;
        for (int kc = 0; kc < span; kc += 32) {
            // stage A: 256 rows x 32 cols
#pragma unroll
            for (int i = 0; i < 4; i++) {
                uint4 v = {0u, 0u, 0u, 0u};
                if (sp[i] >= 0)
                    v = *(const uint4*)(A + (size_t)sp[i] * lda + kc + col8);
                *(uint4*)&As[(i * 64 + srow) * PITCH + col8] = v;
            }
            // stage B: 128 rows x 32 cols
            int kb = TAPS ? (tap * DD + kc) : kc;
#pragma unroll
            for (int i = 0; i < 2; i++) {
                int n = i * 64 + srow;
                uint4 v = *(const uint4*)(Bt + (size_t)(o0 + n) * ldb + kb + col8);
                *(uint4*)&Bs[n * PITCH + col8] = v;
            }
            __syncthreads();

            short8 b[4];
#pragma unroll
            for (int nj = 0; nj < 4; nj++)
                b[nj] = *(const short8*)&Bs[(wc * 64 + nj * 16 + lm) * PITCH + q * 8];
#pragma unroll
            for (int mi = 0; mi < 8; mi++) {
                short8 a = *(const short8*)&As[(wr * 128 + mi * 16 + lm) * PITCH + q * 8];
#pragma unroll
                for (int nj = 0; nj < 4; nj++)
                    acc[mi][nj] = __builtin_amdgcn_mfma_f32_16x16x32_bf16(
                        a, b[nj], acc[mi][nj], 0, 0, 0);
            }
            __syncthreads();
        }
    }

    // epilogue: C/D layout col=lane&15, row=(lane>>4)*4+reg  [m89-verified]
#pragma unroll
    for (int mi = 0; mi < 8; mi++) {
#pragma unroll
        for (int nj = 0; nj < 4; nj++) {
            int col = o0 + wc * 64 + nj * 16 + lm;
#pragma unroll
            for (int r = 0; r < 4; r++) {
                int row = p0 + wr * 128 + mi * 16 + q * 4 + r;
                float v = acc[mi][nj][r];
                size_t idx = (size_t)row * ldc + col;
                if (EPI == 0) {
                    ((unsigned short*)Yv)[idx] = f2bf(v + bias[col]);
                } else if (EPI == 1) {
                    ((unsigned short*)Yv)[idx] = f2bf(gelu_tanh(v + bias[col]));
                } else if (EPI == 2) {
                    ((float*)Yv)[idx] = v + bias[col];
                } else {
                    ((float*)Yv)[idx] += v;
                }
            }
        }
    }
}

// ---------------------------------------------------------------------------
// LN1: out_bf16 = LN(x_f32 + conv_bf16)
__global__ __launch_bounds__(256) void ln1_kernel(const float* __restrict__ x,
                                                  const unsigned short* __restrict__ conv,
                                                  const float* __restrict__ g,
                                                  const float* __restrict__ beta,
                                                  unsigned short* __restrict__ h) {
    int p = blockIdx.x, t = threadIdx.x;
    size_t base = (size_t)p * DD;
    float v0 = x[base + t] + bf2f(conv[base + t]);
    float v1 = x[base + 256 + t] + bf2f(conv[base + 256 + t]);
    float s = v0 + v1, sq = v0 * v0 + v1 * v1;
#pragma unroll
    for (int off = 32; off > 0; off >>= 1) { s += __shfl_xor(s, off); sq += __shfl_xor(sq, off); }
    __shared__ float red[2][4];
    int wid = t >> 6, lane = t & 63;
    if (lane == 0) { red[0][wid] = s; red[1][wid] = sq; }
    __syncthreads();
    float S = red[0][0] + red[0][1] + red[0][2] + red[0][3];
    float SQ = red[1][0] + red[1][1] + red[1][2] + red[1][3];
    float mu = S * (1.f / DD);
    float var = SQ * (1.f / DD) - mu * mu;
    float rs = rsqrtf(var + 1e-5f);
    h[base + t]       = f2bf((v0 - mu) * rs * g[t] + beta[t]);
    h[base + 256 + t] = f2bf((v1 - mu) * rs * g[256 + t] + beta[256 + t]);
}

// LN2: out_f32 = LN(h_bf16 + out_f32) in place
__global__ __launch_bounds__(256) void ln2_kernel(const unsigned short* __restrict__ h,
                                                  float* __restrict__ out,
                                                  const float* __restrict__ g,
                                                  const float* __restrict__ beta) {
    int p = blockIdx.x, t = threadIdx.x;
    size_t base = (size_t)p * DD;
    float v0 = bf2f(h[base + t]) + out[base + t];
    float v1 = bf2f(h[base + 256 + t]) + out[base + 256 + t];
    float s = v0 + v1, sq = v0 * v0 + v1 * v1;
#pragma unroll
    for (int off = 32; off > 0; off >>= 1) { s += __shfl_xor(s, off); sq += __shfl_xor(sq, off); }
    __shared__ float red[2][4];
    int wid = t >> 6, lane = t & 63;
    if (lane == 0) { red[0][wid] = s; red[1][wid] = sq; }
    __syncthreads();
    float S = red[0][0] + red[0][1] + red[0][2] + red[0][3];
    float SQ = red[1][0] + red[1][1] + red[1][2] + red[1][3];
    float mu = S * (1.f / DD);
    float var = SQ * (1.f / DD) - mu * mu;
    float rs = rsqrtf(var + 1e-5f);
    out[base + t]       = (v0 - mu) * rs * g[t] + beta[t];
    out[base + 256 + t] = (v1 - mu) * rs * g[256 + t] + beta[256 + t];
}

// ---------------------------------------------------------------------------
extern "C" void kernel_launch(void* const* d_in, const int* in_sizes, int n_in,
                              void* d_out, int out_size, void* d_ws, size_t ws_size,
                              hipStream_t stream) {
    const float* x     = (const float*)d_in[0];
    const int*   chain = (const int*)d_in[1];
    const float* W3    = (const float*)d_in[2];
    const float* b3    = (const float*)d_in[3];
    const float* W5    = (const float*)d_in[4];
    const float* b5    = (const float*)d_in[5];
    const float* W7    = (const float*)d_in[6];
    const float* b7    = (const float*)d_in[7];
    const float* w1    = (const float*)d_in[8];
    const float* bm1   = (const float*)d_in[9];
    const float* w2    = (const float*)d_in[10];
    const float* bm2   = (const float*)d_in[11];
    const float* g1    = (const float*)d_in[12];
    const float* be1   = (const float*)d_in[13];
    const float* g2    = (const float*)d_in[14];
    const float* be2   = (const float*)d_in[15];
    float* out = (float*)d_out;

    const size_t ACT = (size_t)PTOT * DD * 2;     // 32 MB bf16 activation buffer
    char* ws = (char*)d_ws;
    size_t off = 0;
    unsigned short* Xb   = (unsigned short*)(ws + off); off += ACT;
    unsigned short* buf1 = (unsigned short*)(ws + off); off += ACT;
    unsigned short* buf2 = (unsigned short*)(ws + off); off += ACT;
    unsigned short* w3t  = (unsigned short*)(ws + off); off += (size_t)3 * DD * DD * 2;
    unsigned short* w5t  = (unsigned short*)(ws + off); off += (size_t)5 * DD * DD * 2;
    unsigned short* w7t  = (unsigned short*)(ws + off); off += (size_t)7 * DD * DD * 2;
    unsigned short* w1t  = (unsigned short*)(ws + off); off += (size_t)DD * HID * 2;
    unsigned short* w2t  = (unsigned short*)(ws + off); off += (size_t)DD * HID * 2;
    int* srcp3 = (int*)(ws + off); off += (size_t)PTOT * 3 * 4;
    int* srcp5 = (int*)(ws + off); off += (size_t)PTOT * 5 * 4;
    int* srcp7 = (int*)(ws + off); off += (size_t)PTOT * 7 * 4;
    size_t base_off = off;
    bool full = (ws_size >= base_off + (size_t)PTOT * HID * 2);
    unsigned short* Hb = (unsigned short*)(ws + base_off);  // 32MB chunked / 128MB full

    // prep
    convert_x<<<PTOT * DD / (256 * 4), 256, 0, stream>>>(x, Xb);
    trans_wconv<<<(DD * DD * 3 + 255) / 256, 256, 0, stream>>>(W3, w3t, 3);
    trans_wconv<<<(DD * DD * 5 + 255) / 256, 256, 0, stream>>>(W5, w5t, 5);
    trans_wconv<<<(DD * DD * 7 + 255) / 256, 256, 0, stream>>>(W7, w7t, 7);
    trans_w1<<<DD * HID / 256, 256, 0, stream>>>(w1, w1t);
    trans_w2<<<DD * HID / 256, 256, 0, stream>>>(w2, w2t);
    make_srcp<<<(PTOT * 3 + 255) / 256, 256, 0, stream>>>(chain, srcp3, 3);
    make_srcp<<<(PTOT * 5 + 255) / 256, 256, 0, stream>>>(chain, srcp5, 5);
    make_srcp<<<(PTOT * 7 + 255) / 256, 256, 0, stream>>>(chain, srcp7, 7);

    dim3 gconv(PTOT / 256, DD / 128);   // 128 x 4

    mfma_gemm<3, 0><<<gconv, 256, 0, stream>>>(Xb, DD, srcp3, w3t, 3 * DD, b3, buf1, DD, DD);
    mfma_gemm<5, 0><<<gconv, 256, 0, stream>>>(buf1, DD, srcp5, w5t, 5 * DD, b5, buf2, DD, DD);
    mfma_gemm<7, 0><<<gconv, 256, 0, stream>>>(buf2, DD, srcp7, w7t, 7 * DD, b7, buf1, DD, DD);

    ln1_kernel<<<PTOT, 256, 0, stream>>>(x, buf1, g1, be1, buf2);

    if (full) {
        dim3 g1d(PTOT / 256, HID / 128);   // 128 x 16
        mfma_gemm<0, 1><<<g1d, 256, 0, stream>>>(buf2, DD, nullptr, w1t, DD, bm1,
                                                 Hb, HID, DD);
        mfma_gemm<0, 2><<<gconv, 256, 0, stream>>>(Hb, HID, nullptr, w2t, HID, bm2,
                                                   out, DD, HID);
    } else {
        for (int jc = 0; jc < 4; jc++) {
            mfma_gemm<0, 1><<<gconv, 256, 0, stream>>>(buf2, DD, nullptr,
                                                       w1t + (size_t)jc * DD * DD, DD,
                                                       bm1 + jc * DD, Hb, DD, DD);
            if (jc == 0)
                mfma_gemm<0, 2><<<gconv, 256, 0, stream>>>(Hb, DD, nullptr,
                                                           w2t + jc * DD, HID, bm2,
                                                           out, DD, DD);
            else
                mfma_gemm<0, 3><<<gconv, 256, 0, stream>>>(Hb, DD, nullptr,
                                                           w2t + jc * DD, HID, bm2,
                                                           out, DD, DD);
        }
    }

    ln2_kernel<<<PTOT, 256, 0, stream>>>(buf2, out, g2, be2);
}

// Round 3
// 705.651 us; speedup vs baseline: 9.1010x; 1.3256x over previous
//
#include <hip/hip_runtime.h>
#include <math.h>

#define BB 8
#define LL 4096
#define DD 512
#define PTOT (BB*LL)      // 32768 positions
#define HID  2048

typedef __attribute__((ext_vector_type(8))) short short8;   // 8 bf16 (4 VGPRs)
typedef __attribute__((ext_vector_type(4))) float f32x4;

typedef __attribute__((address_space(1))) const unsigned int gconst_u32;
typedef __attribute__((address_space(3))) unsigned int lds_u32;

__device__ __forceinline__ void gload16(const void* g, void* l) {
    // async global->LDS DMA, 16B per lane; LDS dest = wave-uniform base + lane*16
    __builtin_amdgcn_global_load_lds((gconst_u32*)g, (lds_u32*)l, 16, 0, 0);
}

__device__ __forceinline__ unsigned short f2bf(float f) {
    union { float f; unsigned int u; } v; v.f = f;
    unsigned int r = v.u + 0x7fffu + ((v.u >> 16) & 1u);
    return (unsigned short)(r >> 16);
}
__device__ __forceinline__ float bf2f(unsigned short h) {
    union { unsigned int u; float f; } v; v.u = ((unsigned int)h) << 16;
    return v.f;
}
__device__ __forceinline__ float gelu_tanh(float x) {
    float x3 = x * x * x;
    return 0.5f * x * (1.f + tanhf(0.7978845608028654f * (x + 0.044715f * x3)));
}

// ---------------------------------------------------------------------------
// x fp32 -> bf16; also zero the 256B zero-page (ws is re-poisoned each launch)
__global__ __launch_bounds__(256) void convert_x(const float* __restrict__ x,
                                                 unsigned short* __restrict__ xb,
                                                 unsigned short* __restrict__ zp) {
    int tid = blockIdx.x * 256 + threadIdx.x;
    if (blockIdx.x == 0 && threadIdx.x < 128) zp[threadIdx.x] = 0;
    float4 v = ((const float4*)x)[tid];
    uint2 o;
    o.x = (unsigned int)f2bf(v.x) | ((unsigned int)f2bf(v.y) << 16);
    o.y = (unsigned int)f2bf(v.z) | ((unsigned int)f2bf(v.w) << 16);
    ((uint2*)xb)[tid] = o;
}

// conv W (o,c,k) -> Wt[o][k*512+c] bf16
__global__ __launch_bounds__(256) void trans_wconv(const float* __restrict__ W,
                                                   unsigned short* __restrict__ Wt, int K) {
    int tid = blockIdx.x * 256 + threadIdx.x;
    if (tid >= DD * DD * K) return;
    int o  = tid / (K * DD);
    int kc = tid - o * K * DD;
    int k  = kc >> 9;
    int c  = kc & (DD - 1);
    Wt[tid] = f2bf(W[(o * DD + c) * K + k]);
}

// mlp_w1 (c, n) -> W1t[n][c]
__global__ __launch_bounds__(256) void trans_w1(const float* __restrict__ W,
                                                unsigned short* __restrict__ Wt) {
    int tid = blockIdx.x * 256 + threadIdx.x;   // n*512 + c
    int n = tid >> 9;
    int c = tid & (DD - 1);
    Wt[tid] = f2bf(W[c * HID + n]);
}

// mlp_w2 (h, n) -> W2t[n][h]
__global__ __launch_bounds__(256) void trans_w2(const float* __restrict__ W,
                                                unsigned short* __restrict__ Wt) {
    int tid = blockIdx.x * 256 + threadIdx.x;   // n*2048 + h
    int n = tid >> 11;
    int h = tid & (HID - 1);
    Wt[tid] = f2bf(W[h * DD + n]);
}

// srcp[p*K + k] = p + k - pad if in-range and chain matches, else -1
__global__ __launch_bounds__(256) void make_srcp(const int* __restrict__ chain,
                                                 int* __restrict__ srcp, int K) {
    int tid = blockIdx.x * 256 + threadIdx.x;
    if (tid >= PTOT * K) return;
    int p = tid / K;
    int k = tid - p * K;
    int b = p >> 12;
    int l = p & (LL - 1);
    int pad = (K - 1) >> 1;
    int l2 = l + k - pad;
    bool ok = (l2 >= 0) && (l2 < LL) && (chain[b * LL + l2] == chain[b * LL + l]);
    srcp[tid] = ok ? (p + k - pad) : -1;
}

// ---------------------------------------------------------------------------
// MFMA GEMM: block 256x128, BK=64, 4 waves (2x2), wave tile 128x64 (8x4 frags).
// Staging via global_load_lds(16B) with XOR-swizzled LDS layout:
//   row r is 128B (64 bf16, 8 quads of 16B); source quad qq lives at slot
//   qq ^ (r&7). ds_read_b128 of quad (kk*4+q) then covers each bank-quad
//   exactly 2x across 16 lanes -> conflict-free (2-way aliasing is free).
// EPI: 0 = bf16 out = acc+bias; 1 = bf16 out = gelu(acc+bias);
//      2 = f32 out = acc+bias;  3 = f32 out += acc.
template <int TAPS, int EPI>
__global__ __launch_bounds__(256, 2) void mfma_gemm(
        const unsigned short* __restrict__ A, int lda,
        const int* __restrict__ srcp,
        const unsigned short* __restrict__ Bt, int ldb,
        const float* __restrict__ bias,
        void* __restrict__ Yv, int ldc, int Kspan,
        const unsigned short* __restrict__ zp) {
    __shared__ alignas(16) unsigned short As[256 * 64];   // 32 KB, swizzled
    __shared__ alignas(16) unsigned short Bs[128 * 64];   // 16 KB, swizzled

    int t = threadIdx.x;
    int p0 = blockIdx.x * 256;
    int o0 = blockIdx.y * 128;
    int w = t >> 6, lane = t & 63;
    int wr = w & 1, wc = w >> 1;
    int lm = lane & 15, q = lane >> 4;

    // staging geometry: each instr covers 8 rows x 128B; lane -> (row, slot)
    int lrow8 = lane >> 3;                  // row-within-8
    int qq = (lane & 7) ^ lrow8;            // source quad (slot = lane&7, row&7 = lrow8)

    unsigned short* a_dst = As + w * 4096;  // wave-uniform; instr i at +i*512 shorts
    unsigned short* b_dst = Bs + w * 2048;

    const unsigned short* bgp[4];
#pragma unroll
    for (int j = 0; j < 4; j++)
        bgp[j] = Bt + (size_t)(o0 + w * 32 + j * 8 + lrow8) * ldb + qq * 8;

    f32x4 acc[8][4];
#pragma unroll
    for (int mi = 0; mi < 8; mi++)
#pragma unroll
        for (int nj = 0; nj < 4; nj++) acc[mi][nj] = (f32x4){0.f, 0.f, 0.f, 0.f};

    const int NT = TAPS ? TAPS : 1;
    for (int tap = 0; tap < NT; ++tap) {
        const unsigned short* agp[8];
#pragma unroll
        for (int i = 0; i < 8; i++) {
            int r = p0 + w * 64 + i * 8 + lrow8;
            if (TAPS) {
                int sp = srcp[r * TAPS + tap];
                agp[i] = (sp >= 0) ? (A + (size_t)sp * lda + qq * 8) : nullptr;
            } else {
                agp[i] = A + (size_t)r * lda + qq * 8;
            }
        }
        const int span = TAPS ? DD : Kspan;
        const int kb0  = TAPS ? tap * DD : 0;
        for (int kc = 0; kc < span; kc += 64) {
#pragma unroll
            for (int i = 0; i < 8; i++) {
                const unsigned short* g = agp[i] ? (agp[i] + kc) : zp;
                gload16(g, a_dst + i * 512);
            }
#pragma unroll
            for (int j = 0; j < 4; j++)
                gload16(bgp[j] + kb0 + kc, b_dst + j * 512);
            __syncthreads();

#pragma unroll
            for (int kk = 0; kk < 2; kk++) {
                int sa = ((kk * 4 + q) ^ (lm & 7)) * 8;   // swizzled slot, in shorts
                short8 b[4];
#pragma unroll
                for (int nj = 0; nj < 4; nj++)
                    b[nj] = *(const short8*)&Bs[(wc * 64 + nj * 16 + lm) * 64 + sa];
#pragma unroll
                for (int mi = 0; mi < 8; mi++) {
                    short8 a = *(const short8*)&As[(wr * 128 + mi * 16 + lm) * 64 + sa];
#pragma unroll
                    for (int nj = 0; nj < 4; nj++)
                        acc[mi][nj] = __builtin_amdgcn_mfma_f32_16x16x32_bf16(
                            a, b[nj], acc[mi][nj], 0, 0, 0);
                }
            }
            __syncthreads();
        }
    }

    // epilogue: C/D layout col=lane&15, row=(lane>>4)*4+reg  [m89-verified]
#pragma unroll
    for (int mi = 0; mi < 8; mi++) {
#pragma unroll
        for (int nj = 0; nj < 4; nj++) {
            int col = o0 + wc * 64 + nj * 16 + lm;
#pragma unroll
            for (int r = 0; r < 4; r++) {
                int row = p0 + wr * 128 + mi * 16 + q * 4 + r;
                float v = acc[mi][nj][r];
                size_t idx = (size_t)row * ldc + col;
                if (EPI == 0) {
                    ((unsigned short*)Yv)[idx] = f2bf(v + bias[col]);
                } else if (EPI == 1) {
                    ((unsigned short*)Yv)[idx] = f2bf(gelu_tanh(v + bias[col]));
                } else if (EPI == 2) {
                    ((float*)Yv)[idx] = v + bias[col];
                } else {
                    ((float*)Yv)[idx] += v;
                }
            }
        }
    }
}

// ---------------------------------------------------------------------------
// LN1: out_bf16 = LN(x_f32 + conv_bf16)
__global__ __launch_bounds__(256) void ln1_kernel(const float* __restrict__ x,
                                                  const unsigned short* __restrict__ conv,
                                                  const float* __restrict__ g,
                                                  const float* __restrict__ beta,
                                                  unsigned short* __restrict__ h) {
    int p = blockIdx.x, t = threadIdx.x;
    size_t base = (size_t)p * DD;
    float v0 = x[base + t] + bf2f(conv[base + t]);
    float v1 = x[base + 256 + t] + bf2f(conv[base + 256 + t]);
    float s = v0 + v1, sq = v0 * v0 + v1 * v1;
#pragma unroll
    for (int off = 32; off > 0; off >>= 1) { s += __shfl_xor(s, off); sq += __shfl_xor(sq, off); }
    __shared__ float red[2][4];
    int wid = t >> 6, lane = t & 63;
    if (lane == 0) { red[0][wid] = s; red[1][wid] = sq; }
    __syncthreads();
    float S = red[0][0] + red[0][1] + red[0][2] + red[0][3];
    float SQ = red[1][0] + red[1][1] + red[1][2] + red[1][3];
    float mu = S * (1.f / DD);
    float var = SQ * (1.f / DD) - mu * mu;
    float rs = rsqrtf(var + 1e-5f);
    h[base + t]       = f2bf((v0 - mu) * rs * g[t] + beta[t]);
    h[base + 256 + t] = f2bf((v1 - mu) * rs * g[256 + t] + beta[256 + t]);
}

// LN2: out_f32 = LN(h_bf16 + out_f32) in place
__global__ __launch_bounds__(256) void ln2_kernel(const unsigned short* __restrict__ h,
                                                  float* __restrict__ out,
                                                  const float* __restrict__ g,
                                                  const float* __restrict__ beta) {
    int p = blockIdx.x, t = threadIdx.x;
    size_t base = (size_t)p * DD;
    float v0 = bf2f(h[base + t]) + out[base + t];
    float v1 = bf2f(h[base + 256 + t]) + out[base + 256 + t];
    float s = v0 + v1, sq = v0 * v0 + v1 * v1;
#pragma unroll
    for (int off = 32; off > 0; off >>= 1) { s += __shfl_xor(s, off); sq += __shfl_xor(sq, off); }
    __shared__ float red[2][4];
    int wid = t >> 6, lane = t & 63;
    if (lane == 0) { red[0][wid] = s; red[1][wid] = sq; }
    __syncthreads();
    float S = red[0][0] + red[0][1] + red[0][2] + red[0][3];
    float SQ = red[1][0] + red[1][1] + red[1][2] + red[1][3];
    float mu = S * (1.f / DD);
    float var = SQ * (1.f / DD) - mu * mu;
    float rs = rsqrtf(var + 1e-5f);
    out[base + t]       = (v0 - mu) * rs * g[t] + beta[t];
    out[base + 256 + t] = (v1 - mu) * rs * g[256 + t] + beta[256 + t];
}

// ---------------------------------------------------------------------------
extern "C" void kernel_launch(void* const* d_in, const int* in_sizes, int n_in,
                              void* d_out, int out_size, void* d_ws, size_t ws_size,
                              hipStream_t stream) {
    const float* x     = (const float*)d_in[0];
    const int*   chain = (const int*)d_in[1];
    const float* W3    = (const float*)d_in[2];
    const float* b3    = (const float*)d_in[3];
    const float* W5    = (const float*)d_in[4];
    const float* b5    = (const float*)d_in[5];
    const float* W7    = (const float*)d_in[6];
    const float* b7    = (const float*)d_in[7];
    const float* w1    = (const float*)d_in[8];
    const float* bm1   = (const float*)d_in[9];
    const float* w2    = (const float*)d_in[10];
    const float* bm2   = (const float*)d_in[11];
    const float* g1    = (const float*)d_in[12];
    const float* be1   = (const float*)d_in[13];
    const float* g2    = (const float*)d_in[14];
    const float* be2   = (const float*)d_in[15];
    float* out = (float*)d_out;

    const size_t ACT = (size_t)PTOT * DD * 2;     // 32 MB bf16 activation buffer
    char* ws = (char*)d_ws;
    size_t off = 0;
    unsigned short* Xb   = (unsigned short*)(ws + off); off += ACT;
    unsigned short* buf1 = (unsigned short*)(ws + off); off += ACT;
    unsigned short* buf2 = (unsigned short*)(ws + off); off += ACT;
    unsigned short* w3t  = (unsigned short*)(ws + off); off += (size_t)3 * DD * DD * 2;
    unsigned short* w5t  = (unsigned short*)(ws + off); off += (size_t)5 * DD * DD * 2;
    unsigned short* w7t  = (unsigned short*)(ws + off); off += (size_t)7 * DD * DD * 2;
    unsigned short* w1t  = (unsigned short*)(ws + off); off += (size_t)DD * HID * 2;
    unsigned short* w2t  = (unsigned short*)(ws + off); off += (size_t)DD * HID * 2;
    int* srcp3 = (int*)(ws + off); off += (size_t)PTOT * 3 * 4;
    int* srcp5 = (int*)(ws + off); off += (size_t)PTOT * 5 * 4;
    int* srcp7 = (int*)(ws + off); off += (size_t)PTOT * 7 * 4;
    unsigned short* zp = (unsigned short*)(ws + off); off += 256;
    size_t base_off = off;
    bool full = (ws_size >= base_off + (size_t)PTOT * HID * 2);
    unsigned short* Hb = (unsigned short*)(ws + base_off);  // 32MB chunked / 128MB full

    // prep
    convert_x<<<PTOT * DD / (256 * 4), 256, 0, stream>>>(x, Xb, zp);
    trans_wconv<<<(DD * DD * 3 + 255) / 256, 256, 0, stream>>>(W3, w3t, 3);
    trans_wconv<<<(DD * DD * 5 + 255) / 256, 256, 0, stream>>>(W5, w5t, 5);
    trans_wconv<<<(DD * DD * 7 + 255) / 256, 256, 0, stream>>>(W7, w7t, 7);
    trans_w1<<<DD * HID / 256, 256, 0, stream>>>(w1, w1t);
    trans_w2<<<DD * HID / 256, 256, 0, stream>>>(w2, w2t);
    make_srcp<<<(PTOT * 3 + 255) / 256, 256, 0, stream>>>(chain, srcp3, 3);
    make_srcp<<<(PTOT * 5 + 255) / 256, 256, 0, stream>>>(chain, srcp5, 5);
    make_srcp<<<(PTOT * 7 + 255) / 256, 256, 0, stream>>>(chain, srcp7, 7);

    dim3 gconv(PTOT / 256, DD / 128);   // 128 x 4

    mfma_gemm<3, 0><<<gconv, 256, 0, stream>>>(Xb, DD, srcp3, w3t, 3 * DD, b3, buf1, DD, DD, zp);
    mfma_gemm<5, 0><<<gconv, 256, 0, stream>>>(buf1, DD, srcp5, w5t, 5 * DD, b5, buf2, DD, DD, zp);
    mfma_gemm<7, 0><<<gconv, 256, 0, stream>>>(buf2, DD, srcp7, w7t, 7 * DD, b7, buf1, DD, DD, zp);

    ln1_kernel<<<PTOT, 256, 0, stream>>>(x, buf1, g1, be1, buf2);

    if (full) {
        dim3 g1d(PTOT / 256, HID / 128);   // 128 x 16
        mfma_gemm<0, 1><<<g1d, 256, 0, stream>>>(buf2, DD, nullptr, w1t, DD, bm1,
                                                 Hb, HID, DD, zp);
        mfma_gemm<0, 2><<<gconv, 256, 0, stream>>>(Hb, HID, nullptr, w2t, HID, bm2,
                                                   out, DD, HID, zp);
    } else {
        for (int jc = 0; jc < 4; jc++) {
            mfma_gemm<0, 1><<<gconv, 256, 0, stream>>>(buf2, DD, nullptr,
                                                       w1t + (size_t)jc * DD * DD, DD,
                                                       bm1 + jc * DD, Hb, DD, DD, zp);
            if (jc == 0)
                mfma_gemm<0, 2><<<gconv, 256, 0, stream>>>(Hb, DD, nullptr,
                                                           w2t + jc * DD, HID, bm2,
                                                           out, DD, DD, zp);
            else
                mfma_gemm<0, 3><<<gconv, 256, 0, stream>>>(Hb, DD, nullptr,
                                                           w2t + jc * DD, HID, bm2,
                                                           out, DD, DD, zp);
        }
    }

    ln2_kernel<<<PTOT, 256, 0, stream>>>(buf2, out, g2, be2);
}

// Round 4
// 693.560 us; speedup vs baseline: 9.2597x; 1.0174x over previous
//
#include <hip/hip_runtime.h>
#include <math.h>

#define BB 8
#define LL 4096
#define DD 512
#define PTOT (BB*LL)      // 32768 positions
#define HID  2048

typedef __attribute__((ext_vector_type(8))) short short8;   // 8 bf16 (4 VGPRs)
typedef __attribute__((ext_vector_type(4))) float f32x4;

typedef __attribute__((address_space(1))) const unsigned int gconst_u32;
typedef __attribute__((address_space(3))) unsigned int lds_u32;

__device__ __forceinline__ void gload16(const void* g, void* l) {
    // async global->LDS DMA, 16B per lane; LDS dest = wave-uniform base + lane*16
    __builtin_amdgcn_global_load_lds((gconst_u32*)g, (lds_u32*)l, 16, 0, 0);
}

__device__ __forceinline__ unsigned short f2bf(float f) {
    union { float f; unsigned int u; } v; v.f = f;
    unsigned int r = v.u + 0x7fffu + ((v.u >> 16) & 1u);
    return (unsigned short)(r >> 16);
}
__device__ __forceinline__ float bf2f(unsigned short h) {
    union { unsigned int u; float f; } v; v.u = ((unsigned int)h) << 16;
    return v.f;
}
// gelu(x) = x * sigmoid(2*0.79788456*(x + 0.044715 x^3)); exp/rcp via HW transcendentals
__device__ __forceinline__ float gelu_fast(float x) {
    float x2 = x * x;
    float t  = x * fmaf(0.044715f, x2, 1.0f);
    float e  = __builtin_amdgcn_exp2f(-2.3021143f * t);   // e^{-2z}
    return x * __builtin_amdgcn_rcpf(1.0f + e);
}

// ---------------------------------------------------------------------------
// x fp32 -> bf16; also zero the 256B zero-page (ws is re-poisoned each launch)
__global__ __launch_bounds__(256) void convert_x(const float* __restrict__ x,
                                                 unsigned short* __restrict__ xb,
                                                 unsigned short* __restrict__ zp) {
    int tid = blockIdx.x * 256 + threadIdx.x;
    if (blockIdx.x == 0 && threadIdx.x < 128) zp[threadIdx.x] = 0;
    float4 v = ((const float4*)x)[tid];
    uint2 o;
    o.x = (unsigned int)f2bf(v.x) | ((unsigned int)f2bf(v.y) << 16);
    o.y = (unsigned int)f2bf(v.z) | ((unsigned int)f2bf(v.w) << 16);
    ((uint2*)xb)[tid] = o;
}

// conv W (o,c,k) -> Wt[o][k*512+c] bf16
__global__ __launch_bounds__(256) void trans_wconv(const float* __restrict__ W,
                                                   unsigned short* __restrict__ Wt, int K) {
    int tid = blockIdx.x * 256 + threadIdx.x;
    if (tid >= DD * DD * K) return;
    int o  = tid / (K * DD);
    int kc = tid - o * K * DD;
    int k  = kc >> 9;
    int c  = kc & (DD - 1);
    Wt[tid] = f2bf(W[(o * DD + c) * K + k]);
}

// mlp_w1 (c, n) -> W1t[n][c]
__global__ __launch_bounds__(256) void trans_w1(const float* __restrict__ W,
                                                unsigned short* __restrict__ Wt) {
    int tid = blockIdx.x * 256 + threadIdx.x;   // n*512 + c
    int n = tid >> 9;
    int c = tid & (DD - 1);
    Wt[tid] = f2bf(W[c * HID + n]);
}

// mlp_w2 (h, n) -> W2t[n][h]
__global__ __launch_bounds__(256) void trans_w2(const float* __restrict__ W,
                                                unsigned short* __restrict__ Wt) {
    int tid = blockIdx.x * 256 + threadIdx.x;   // n*2048 + h
    int n = tid >> 11;
    int h = tid & (HID - 1);
    Wt[tid] = f2bf(W[h * DD + n]);
}

// srcp[p*K + k] = p + k - pad if in-range and chain matches, else -1
__global__ __launch_bounds__(256) void make_srcp(const int* __restrict__ chain,
                                                 int* __restrict__ srcp, int K) {
    int tid = blockIdx.x * 256 + threadIdx.x;
    if (tid >= PTOT * K) return;
    int p = tid / K;
    int k = tid - p * K;
    int b = p >> 12;
    int l = p & (LL - 1);
    int pad = (K - 1) >> 1;
    int l2 = l + k - pad;
    bool ok = (l2 >= 0) && (l2 < LL) && (chain[b * LL + l2] == chain[b * LL + l]);
    srcp[tid] = ok ? (p + k - pad) : -1;
}

// ---------------------------------------------------------------------------
// MFMA GEMM: block 128x128, BK=64, 4 waves (2x2), wave tile 64x64 (4x4 frags,
// 64 AGPR acc -> 3 blocks/CU with launch_bounds(256,3)).
// Staging via global_load_lds(16B), XOR-swizzled LDS rows (128B row, quad qq
// at slot qq^(r&7)); ds_read_b128 is 2-way-aliased only (free, m136; 0
// conflicts measured round 3).
// EPI: 0 = bf16 out = acc+bias; 1 = bf16 out = gelu(acc+bias);
//      2 = f32 out = acc+bias;  3 = f32 out += acc.
template <int TAPS, int EPI>
__global__ __launch_bounds__(256, 3) void mfma_gemm(
        const unsigned short* __restrict__ A, int lda,
        const int* __restrict__ srcp,
        const unsigned short* __restrict__ Bt, int ldb,
        const float* __restrict__ bias,
        void* __restrict__ Yv, int ldc, int Kspan,
        const unsigned short* __restrict__ zp) {
    __shared__ alignas(16) unsigned short As[128 * 64];   // 16 KB, swizzled
    __shared__ alignas(16) unsigned short Bs[128 * 64];   // 16 KB, swizzled

    int t = threadIdx.x;
    int p0 = blockIdx.x * 128;
    int o0 = blockIdx.y * 128;
    int w = t >> 6, lane = t & 63;
    int wr = w & 1, wc = w >> 1;
    int lm = lane & 15, q = lane >> 4;

    // staging geometry: each instr covers 8 rows x 128B; lane -> (row, slot)
    int lrow8 = lane >> 3;                  // row-within-8
    int qq = (lane & 7) ^ lrow8;            // source quad (slot = lane&7)

    unsigned short* a_dst = As + w * 2048;  // wave w stages rows [w*32, w*32+32)
    unsigned short* b_dst = Bs + w * 2048;

    int boff[4];
#pragma unroll
    for (int j = 0; j < 4; j++)
        boff[j] = (o0 + w * 32 + j * 8 + lrow8) * ldb + qq * 8;

    f32x4 acc[4][4];
#pragma unroll
    for (int mi = 0; mi < 4; mi++)
#pragma unroll
        for (int nj = 0; nj < 4; nj++) acc[mi][nj] = (f32x4){0.f, 0.f, 0.f, 0.f};

    const int NT = TAPS ? TAPS : 1;
    for (int tap = 0; tap < NT; ++tap) {
        int aoff[4];
#pragma unroll
        for (int i = 0; i < 4; i++) {
            int r = p0 + w * 32 + i * 8 + lrow8;
            int sp = TAPS ? srcp[r * TAPS + tap] : r;
            aoff[i] = (sp >= 0) ? (sp * lda + qq * 8) : -1;
        }
        const int span = TAPS ? DD : Kspan;
        const int kb0  = TAPS ? tap * DD : 0;
        for (int kc = 0; kc < span; kc += 64) {
#pragma unroll
            for (int i = 0; i < 4; i++) {
                const unsigned short* g = (aoff[i] >= 0) ? (A + aoff[i] + kc) : zp;
                gload16(g, a_dst + i * 512);
            }
#pragma unroll
            for (int j = 0; j < 4; j++)
                gload16(Bt + boff[j] + kb0 + kc, b_dst + j * 512);
            __syncthreads();

#pragma unroll
            for (int kk = 0; kk < 2; kk++) {
                int sa = ((kk * 4 + q) ^ (lm & 7)) * 8;   // swizzled slot, shorts
                short8 b[4];
#pragma unroll
                for (int nj = 0; nj < 4; nj++)
                    b[nj] = *(const short8*)&Bs[(wc * 64 + nj * 16 + lm) * 64 + sa];
#pragma unroll
                for (int mi = 0; mi < 4; mi++) {
                    short8 a = *(const short8*)&As[(wr * 64 + mi * 16 + lm) * 64 + sa];
#pragma unroll
                    for (int nj = 0; nj < 4; nj++)
                        acc[mi][nj] = __builtin_amdgcn_mfma_f32_16x16x32_bf16(
                            a, b[nj], acc[mi][nj], 0, 0, 0);
                }
            }
            __syncthreads();
        }
    }

    // epilogue: C/D layout col=lane&15, row=(lane>>4)*4+reg  [m89-verified]
#pragma unroll
    for (int mi = 0; mi < 4; mi++) {
#pragma unroll
        for (int nj = 0; nj < 4; nj++) {
            int col = o0 + wc * 64 + nj * 16 + lm;
#pragma unroll
            for (int r = 0; r < 4; r++) {
                int row = p0 + wr * 64 + mi * 16 + q * 4 + r;
                float v = acc[mi][nj][r];
                size_t idx = (size_t)row * ldc + col;
                if (EPI == 0) {
                    ((unsigned short*)Yv)[idx] = f2bf(v + bias[col]);
                } else if (EPI == 1) {
                    ((unsigned short*)Yv)[idx] = f2bf(gelu_fast(v + bias[col]));
                } else if (EPI == 2) {
                    ((float*)Yv)[idx] = v + bias[col];
                } else {
                    ((float*)Yv)[idx] += v;
                }
            }
        }
    }
}

// ---------------------------------------------------------------------------
// LN1: out_bf16 = LN(x_f32 + conv_bf16)
__global__ __launch_bounds__(256) void ln1_kernel(const float* __restrict__ x,
                                                  const unsigned short* __restrict__ conv,
                                                  const float* __restrict__ g,
                                                  const float* __restrict__ beta,
                                                  unsigned short* __restrict__ h) {
    int p = blockIdx.x, t = threadIdx.x;
    size_t base = (size_t)p * DD;
    float v0 = x[base + t] + bf2f(conv[base + t]);
    float v1 = x[base + 256 + t] + bf2f(conv[base + 256 + t]);
    float s = v0 + v1, sq = v0 * v0 + v1 * v1;
#pragma unroll
    for (int off = 32; off > 0; off >>= 1) { s += __shfl_xor(s, off); sq += __shfl_xor(sq, off); }
    __shared__ float red[2][4];
    int wid = t >> 6, lane = t & 63;
    if (lane == 0) { red[0][wid] = s; red[1][wid] = sq; }
    __syncthreads();
    float S = red[0][0] + red[0][1] + red[0][2] + red[0][3];
    float SQ = red[1][0] + red[1][1] + red[1][2] + red[1][3];
    float mu = S * (1.f / DD);
    float var = SQ * (1.f / DD) - mu * mu;
    float rs = rsqrtf(var + 1e-5f);
    h[base + t]       = f2bf((v0 - mu) * rs * g[t] + beta[t]);
    h[base + 256 + t] = f2bf((v1 - mu) * rs * g[256 + t] + beta[256 + t]);
}

// LN2: out_f32 = LN(h_bf16 + out_f32) in place
__global__ __launch_bounds__(256) void ln2_kernel(const unsigned short* __restrict__ h,
                                                  float* __restrict__ out,
                                                  const float* __restrict__ g,
                                                  const float* __restrict__ beta) {
    int p = blockIdx.x, t = threadIdx.x;
    size_t base = (size_t)p * DD;
    float v0 = bf2f(h[base + t]) + out[base + t];
    float v1 = bf2f(h[base + 256 + t]) + out[base + 256 + t];
    float s = v0 + v1, sq = v0 * v0 + v1 * v1;
#pragma unroll
    for (int off = 32; off > 0; off >>= 1) { s += __shfl_xor(s, off); sq += __shfl_xor(sq, off); }
    __shared__ float red[2][4];
    int wid = t >> 6, lane = t & 63;
    if (lane == 0) { red[0][wid] = s; red[1][wid] = sq; }
    __syncthreads();
    float S = red[0][0] + red[0][1] + red[0][2] + red[0][3];
    float SQ = red[1][0] + red[1][1] + red[1][2] + red[1][3];
    float mu = S * (1.f / DD);
    float var = SQ * (1.f / DD) - mu * mu;
    float rs = rsqrtf(var + 1e-5f);
    out[base + t]       = (v0 - mu) * rs * g[t] + beta[t];
    out[base + 256 + t] = (v1 - mu) * rs * g[256 + t] + beta[256 + t];
}

// ---------------------------------------------------------------------------
extern "C" void kernel_launch(void* const* d_in, const int* in_sizes, int n_in,
                              void* d_out, int out_size, void* d_ws, size_t ws_size,
                              hipStream_t stream) {
    const float* x     = (const float*)d_in[0];
    const int*   chain = (const int*)d_in[1];
    const float* W3    = (const float*)d_in[2];
    const float* b3    = (const float*)d_in[3];
    const float* W5    = (const float*)d_in[4];
    const float* b5    = (const float*)d_in[5];
    const float* W7    = (const float*)d_in[6];
    const float* b7    = (const float*)d_in[7];
    const float* w1    = (const float*)d_in[8];
    const float* bm1   = (const float*)d_in[9];
    const float* w2    = (const float*)d_in[10];
    const float* bm2   = (const float*)d_in[11];
    const float* g1    = (const float*)d_in[12];
    const float* be1   = (const float*)d_in[13];
    const float* g2    = (const float*)d_in[14];
    const float* be2   = (const float*)d_in[15];
    float* out = (float*)d_out;

    const size_t ACT = (size_t)PTOT * DD * 2;     // 32 MB bf16 activation buffer
    char* ws = (char*)d_ws;
    size_t off = 0;
    unsigned short* Xb   = (unsigned short*)(ws + off); off += ACT;
    unsigned short* buf1 = (unsigned short*)(ws + off); off += ACT;
    unsigned short* buf2 = (unsigned short*)(ws + off); off += ACT;
    unsigned short* w3t  = (unsigned short*)(ws + off); off += (size_t)3 * DD * DD * 2;
    unsigned short* w5t  = (unsigned short*)(ws + off); off += (size_t)5 * DD * DD * 2;
    unsigned short* w7t  = (unsigned short*)(ws + off); off += (size_t)7 * DD * DD * 2;
    unsigned short* w1t  = (unsigned short*)(ws + off); off += (size_t)DD * HID * 2;
    unsigned short* w2t  = (unsigned short*)(ws + off); off += (size_t)DD * HID * 2;
    int* srcp3 = (int*)(ws + off); off += (size_t)PTOT * 3 * 4;
    int* srcp5 = (int*)(ws + off); off += (size_t)PTOT * 5 * 4;
    int* srcp7 = (int*)(ws + off); off += (size_t)PTOT * 7 * 4;
    unsigned short* zp = (unsigned short*)(ws + off); off += 256;
    size_t base_off = off;
    bool full = (ws_size >= base_off + (size_t)PTOT * HID * 2);
    unsigned short* Hb = (unsigned short*)(ws + base_off);  // 32MB chunked / 128MB full

    // prep
    convert_x<<<PTOT * DD / (256 * 4), 256, 0, stream>>>(x, Xb, zp);
    trans_wconv<<<(DD * DD * 3 + 255) / 256, 256, 0, stream>>>(W3, w3t, 3);
    trans_wconv<<<(DD * DD * 5 + 255) / 256, 256, 0, stream>>>(W5, w5t, 5);
    trans_wconv<<<(DD * DD * 7 + 255) / 256, 256, 0, stream>>>(W7, w7t, 7);
    trans_w1<<<DD * HID / 256, 256, 0, stream>>>(w1, w1t);
    trans_w2<<<DD * HID / 256, 256, 0, stream>>>(w2, w2t);
    make_srcp<<<(PTOT * 3 + 255) / 256, 256, 0, stream>>>(chain, srcp3, 3);
    make_srcp<<<(PTOT * 5 + 255) / 256, 256, 0, stream>>>(chain, srcp5, 5);
    make_srcp<<<(PTOT * 7 + 255) / 256, 256, 0, stream>>>(chain, srcp7, 7);

    dim3 gconv(PTOT / 128, DD / 128);   // 256 x 4

    mfma_gemm<3, 0><<<gconv, 256, 0, stream>>>(Xb, DD, srcp3, w3t, 3 * DD, b3, buf1, DD, DD, zp);
    mfma_gemm<5, 0><<<gconv, 256, 0, stream>>>(buf1, DD, srcp5, w5t, 5 * DD, b5, buf2, DD, DD, zp);
    mfma_gemm<7, 0><<<gconv, 256, 0, stream>>>(buf2, DD, srcp7, w7t, 7 * DD, b7, buf1, DD, DD, zp);

    ln1_kernel<<<PTOT, 256, 0, stream>>>(x, buf1, g1, be1, buf2);

    if (full) {
        dim3 g1d(PTOT / 128, HID / 128);   // 256 x 16
        mfma_gemm<0, 1><<<g1d, 256, 0, stream>>>(buf2, DD, nullptr, w1t, DD, bm1,
                                                 Hb, HID, DD, zp);
        mfma_gemm<0, 2><<<gconv, 256, 0, stream>>>(Hb, HID, nullptr, w2t, HID, bm2,
                                                   out, DD, HID, zp);
    } else {
        for (int jc = 0; jc < 4; jc++) {
            mfma_gemm<0, 1><<<gconv, 256, 0, stream>>>(buf2, DD, nullptr,
                                                       w1t + (size_t)jc * DD * DD, DD,
                                                       bm1 + jc * DD, Hb, DD, DD, zp);
            if (jc == 0)
                mfma_gemm<0, 2><<<gconv, 256, 0, stream>>>(Hb, DD, nullptr,
                                                           w2t + jc * DD, HID, bm2,
                                                           out, DD, DD, zp);
            else
                mfma_gemm<0, 3><<<gconv, 256, 0, stream>>>(Hb, DD, nullptr,
                                                           w2t + jc * DD, HID, bm2,
                                                           out, DD, DD, zp);
        }
    }

    ln2_kernel<<<PTOT, 256, 0, stream>>>(buf2, out, g2, be2);
}